// Round 6
// baseline (686.797 us; speedup 1.0000x reference)
//
#include <hip/hip_runtime.h>

typedef __attribute__((ext_vector_type(8))) short short8;
typedef __attribute__((ext_vector_type(4))) float f32x4;

// fp32 -> bf16 bits, round-to-nearest-even
__device__ __forceinline__ short f2bf(float f) {
    unsigned u = __builtin_bit_cast(unsigned, f);
    u += 0x7fffu + ((u >> 16) & 1u);
    return (short)(u >> 16);
}

// Kernel 1: W_eff = sum_r s_r * W_r, stored TRANSPOSED as bf16: WT[n*128+k].
__global__ void weff_kernel(const float* __restrict__ W,
                            const float* __restrict__ S,
                            short* __restrict__ WT) {
    int idx = blockIdx.x * 256 + threadIdx.x;   // 0..16383 == k*128 + n
    int k = idx >> 7;
    int n = idx & 127;
    float acc = 0.f;
#pragma unroll
    for (int r = 0; r < 8; ++r) acc += S[r] * W[r * 16384 + idx];
    WT[n * 128 + k] = f2bf(acc);
}

// Kernel 2: C[M,128] = A[M,128] @ W_eff[128,128], bf16 MFMA, fp32 accumulate.
// 512-thread blocks (8 waves) so the 34.8KB B-LDS is amortized over 2x the
// waves of the 256-thread version: 3 blocks/CU x 8 waves = 24 waves/CU
// (was 16). Waves are fully independent after the one staging barrier: each
// wave grid-strides over 16-row tiles (tail quantum 16 rows, not 128).
// Inner loop identical to the best-measured round-2 version (205us,
// 3.15 TB/s): swapped-operand MFMA -> lane holds C[row=r16][col t*16+quad*4
// +0..3], direct nt f32x4 stores (full 64B sectors per instr per row).
#define BSTRIDE 136   // 128 + 8 bf16 pad: 16B-aligned, 2-way (free) LDS banking

__global__ __launch_bounds__(512, 6) void gemm_kernel(const float* __restrict__ A,
                                                      const short* __restrict__ WT,
                                                      float* __restrict__ C,
                                                      int N, int nitems) {
    __shared__ __align__(16) short Bs[128 * BSTRIDE];

    int tid = threadIdx.x;
    // Stage W_eff^T (bf16) into padded LDS ONCE per persistent block.
#pragma unroll
    for (int itv = 0; itv < 4; ++itv) {
        int chunk = itv * 512 + tid;           // 0..2047
        int n  = chunk >> 4;                   // row of WT (output col)
        int kc = chunk & 15;                   // which 8-element k chunk
        *(short8*)&Bs[n * BSTRIDE + kc * 8] = ((const short8*)WT)[chunk];
    }
    __syncthreads();

    int wave = tid >> 6;
    int lane = tid & 63;
    int quad = lane >> 4;
    int r16  = lane & 15;

    const short* bbase = &Bs[r16 * BSTRIDE];   // + t*16*BSTRIDE + kk*32 + quad*8

    int gw = blockIdx.x * 8 + wave;            // global wave id
    int nw = gridDim.x * 8;                    // total waves

    f32x4 cur[8], nxt[8];

    // Prologue: issue loads for first 16-row tile.
    {
        long rowA = (long)gw * 16 + r16;
        if (rowA >= N) rowA = N - 1;           // clamp: junk rows never stored
        const float* arow = A + rowA * 128;
#pragma unroll
        for (int kk = 0; kk < 4; ++kk) {
            cur[kk * 2]     = *(const f32x4*)(arow + kk * 32 + quad * 8);
            cur[kk * 2 + 1] = *(const f32x4*)(arow + kk * 32 + quad * 8 + 4);
        }
    }

    for (int it = gw; it < nitems; it += nw) {
        // Prefetch next tile's A into nxt (in flight during compute below).
        int itn = it + nw;
        if (itn < nitems) {
            long rowA = (long)itn * 16 + r16;
            if (rowA >= N) rowA = N - 1;
            const float* arow = A + rowA * 128;
#pragma unroll
            for (int kk = 0; kk < 4; ++kk) {
                nxt[kk * 2]     = *(const f32x4*)(arow + kk * 32 + quad * 8);
                nxt[kk * 2 + 1] = *(const f32x4*)(arow + kk * 32 + quad * 8 + 4);
            }
        }

        f32x4 acc[8];
#pragma unroll
        for (int t = 0; t < 8; ++t) acc[t] = (f32x4)(0.f);

#pragma unroll
        for (int kk = 0; kk < 4; ++kk) {
            f32x4 p = cur[kk * 2];
            f32x4 q = cur[kk * 2 + 1];
            short8 afrag;
            afrag[0] = f2bf(p[0]); afrag[1] = f2bf(p[1]);
            afrag[2] = f2bf(p[2]); afrag[3] = f2bf(p[3]);
            afrag[4] = f2bf(q[0]); afrag[5] = f2bf(q[1]);
            afrag[6] = f2bf(q[2]); afrag[7] = f2bf(q[3]);
            const short* bk = bbase + kk * 32 + quad * 8;
#pragma unroll
            for (int t = 0; t < 8; ++t) {
                // B frag: WT[(t*16+r16)][kk*32 + quad*8 .. +7]
                short8 bfrag = *(const short8*)(bk + t * 16 * BSTRIDE);
                // Swapped operands: D[n][m] = C[m][n] -> lane holds
                // C[row = r16][col = t*16 + quad*4 + reg]
                acc[t] = __builtin_amdgcn_mfma_f32_16x16x32_bf16(bfrag, afrag, acc[t], 0, 0, 0);
            }
        }

        long row = (long)it * 16 + r16;
        if (row < N) {
            float* crow = C + row * 128 + quad * 4;
#pragma unroll
            for (int t = 0; t < 8; ++t) {
                __builtin_nontemporal_store(acc[t], (f32x4*)(crow + t * 16));
            }
        }

#pragma unroll
        for (int i = 0; i < 8; ++i) cur[i] = nxt[i];
    }
}

extern "C" void kernel_launch(void* const* d_in, const int* in_sizes, int n_in,
                              void* d_out, int out_size, void* d_ws, size_t ws_size,
                              hipStream_t stream) {
    const float* inputs = (const float*)d_in[0];     // [N,128] fp32
    const float* W      = (const float*)d_in[1];     // [8,128,128] fp32
    const float* S      = (const float*)d_in[2];     // [8,1] fp32
    float* out = (float*)d_out;                      // [N,128] fp32
    short* WT  = (short*)d_ws;                       // [128,128] bf16 (W_eff^T)

    int N = in_sizes[0] / 128;

    weff_kernel<<<64, 256, 0, stream>>>(W, S, WT);

    int nitems = (N + 15) / 16;                      // 16-row tiles
    int grid = 768;                                  // 3 blocks/CU x 256 CU
    int maxg = (nitems + 7) / 8;
    if (grid > maxg) grid = maxg;
    gemm_kernel<<<grid, 512, 0, stream>>>(inputs, WT, out, N, nitems);
}